// Round 4
// baseline (9867.702 us; speedup 1.0000x reference)
//
#include <hip/hip_runtime.h>
#include <cstdint>
#include <cstddef>

#define B_ 2
#define S_ 2048
#define D_ 1024
#define H_ 16
#define DH_ 64
#define FF_ 4096
#define M_ (B_*S_)
#define MB_ ((size_t)1 << 20)

using u16 = unsigned short;
using short8 = __attribute__((ext_vector_type(8))) short;

__device__ __forceinline__ float bf2f(u16 u) {
    return __uint_as_float(((uint32_t)u) << 16);
}
__device__ __forceinline__ u16 f2bf(float f) {
    uint32_t u = __float_as_uint(f);
    u += 0x7fffu + ((u >> 16) & 1u);   // RNE
    return (u16)(u >> 16);
}
// polymorphic external-input load: f32 flag ? float : bf16
__device__ __forceinline__ float ldx(const void* p, size_t i, int f32) {
    return f32 ? ((const float*)p)[i] : bf2f(((const u16*)p)[i]);
}

// ---------------------------------------------------------------------------
// dtype sniff: probe = WQ (1M float elements). Interpreted as u16[], even
// indices of f32 data are low-mantissa bits -> random exponents (NaN/Inf/
// denormal/huge certain over 500k samples). True bf16 xavier data has none.
// flag=1 -> external buffers are f32; flag=0 -> bf16.
// ---------------------------------------------------------------------------
__global__ void sniff_dtype(const u16* __restrict__ probe, int* __restrict__ flag) {
    __shared__ int hit[256];
    int h = 0;
    for (int i = threadIdx.x * 2; i < (1 << 20); i += 512) {  // even u16 idx, < 2MB
        const u16 v = probe[i];
        const int e = (v >> 7) & 0xFF;
        if (e == 0xFF) h = 1;                       // inf/nan exponent
        if (e == 0 && (v & 0x7FFF)) h = 1;          // denormal
        if (fabsf(bf2f(v)) > 1e4f) h = 1;           // absurd magnitude
    }
    hit[threadIdx.x] = h;
    __syncthreads();
    if (threadIdx.x == 0) {
        int any = 0;
        for (int i = 0; i < 256; ++i) any |= hit[i];
        *flag = any;
    }
}

// ---------------------------------------------------------------------------
// Naive GEMM: C(MxN) = A(MxK) @ W(KxN) + bias. W in KxN layout (coalesced).
// A external (poly) iff a_ext; W/bias always external (poly). C internal bf16.
// ---------------------------------------------------------------------------
template<bool GELU>
__global__ __launch_bounds__(256) void gemm_naive(
    const void* __restrict__ A, int a_ext,
    const void* __restrict__ W, const void* __restrict__ bias,
    u16* __restrict__ C, int M, int N, int K, const int* __restrict__ flag)
{
    const int f32 = *flag;
    const int af = a_ext ? f32 : 0;
    __shared__ float As[64][17];
    __shared__ float Bs[16][65];
    const int t = threadIdx.x;
    const int tx = t & 15, ty = t >> 4;
    const size_t m0 = (size_t)blockIdx.y * 64, n0 = (size_t)blockIdx.x * 64;

    float acc[4][4];
#pragma unroll
    for (int i = 0; i < 4; ++i)
#pragma unroll
        for (int j = 0; j < 4; ++j) acc[i][j] = 0.f;

    for (int k0 = 0; k0 < K; k0 += 16) {
#pragma unroll
        for (int e = 0; e < 4; ++e) {
            const int idx = t + e * 256;
            const int r = idx >> 4, c = idx & 15;
            As[r][c] = ldx(A, (m0 + r) * (size_t)K + k0 + c, af);
        }
#pragma unroll
        for (int e = 0; e < 4; ++e) {
            const int idx = t + e * 256;
            const int r = idx >> 6, c = idx & 63;
            Bs[r][c] = ldx(W, (size_t)(k0 + r) * N + n0 + c, f32);
        }
        __syncthreads();
#pragma unroll
        for (int kk = 0; kk < 16; ++kk) {
            float a[4], b[4];
#pragma unroll
            for (int i = 0; i < 4; ++i) a[i] = As[ty * 4 + i][kk];
#pragma unroll
            for (int j = 0; j < 4; ++j) b[j] = Bs[kk][tx * 4 + j];
#pragma unroll
            for (int i = 0; i < 4; ++i)
#pragma unroll
                for (int j = 0; j < 4; ++j) acc[i][j] += a[i] * b[j];
        }
        __syncthreads();
    }

#pragma unroll
    for (int i = 0; i < 4; ++i) {
        const size_t r = m0 + ty * 4 + i;
#pragma unroll
        for (int j = 0; j < 4; ++j) {
            const size_t c = n0 + tx * 4 + j;
            float v = acc[i][j] + ldx(bias, c, f32);
            if (GELU) v = 0.5f * v * (1.f + erff(v * 0.70710678118f));
            C[r * (size_t)N + c] = f2bf(v);
        }
    }
}

// ---------------------------------------------------------------------------
// Naive attention: one block (256 thr) per (b, h, q). All tensor inputs are
// internal bf16; mask is int32.
// ---------------------------------------------------------------------------
__global__ __launch_bounds__(256) void attn_naive(
    const u16* __restrict__ Q, const u16* __restrict__ Kg,
    const u16* __restrict__ Vg, const int* __restrict__ mask,
    u16* __restrict__ O)
{
    __shared__ float sc[S_];
    __shared__ float qv[DH_];
    __shared__ float rbuf[4], rbuf2[4];
    __shared__ float ored[256];

    const int t = threadIdx.x;
    const int w = t >> 6, lane = t & 63;
    const int q = blockIdx.x;
    const int b = blockIdx.y >> 4, h = blockIdx.y & 15;
    const size_t rowQ = (size_t)(b * S_ + q);

    if (t < DH_) qv[t] = bf2f(Q[rowQ * D_ + h * 64 + t]);
    __syncthreads();

    const int* mp = mask + b * S_;
    for (int k = t; k < S_; k += 256) {
        const u16* Kp = Kg + ((size_t)(b * S_ + k)) * D_ + h * 64;
        float s = 0.f;
#pragma unroll
        for (int d8 = 0; d8 < 8; ++d8) {
            const short8 kv = *(const short8*)(Kp + d8 * 8);
#pragma unroll
            for (int j = 0; j < 8; ++j) s += qv[d8 * 8 + j] * bf2f(((const u16*)&kv)[j]);
        }
        sc[k] = (mp[k] == 0) ? -1e30f : s * 0.125f;
    }
    __syncthreads();

    float pm = -1e30f;
    for (int k = t; k < S_; k += 256) pm = fmaxf(pm, sc[k]);
#pragma unroll
    for (int off = 32; off >= 1; off >>= 1) pm = fmaxf(pm, __shfl_xor(pm, off));
    if (lane == 0) rbuf[w] = pm;
    __syncthreads();
    const float mx = fmaxf(fmaxf(rbuf[0], rbuf[1]), fmaxf(rbuf[2], rbuf[3]));

    float ps = 0.f;
    for (int k = t; k < S_; k += 256) {
        const float p = __expf(sc[k] - mx);
        sc[k] = p; ps += p;
    }
#pragma unroll
    for (int off = 32; off >= 1; off >>= 1) ps += __shfl_xor(ps, off);
    if (lane == 0) rbuf2[w] = ps;
    __syncthreads();
    const float sum = rbuf2[0] + rbuf2[1] + rbuf2[2] + rbuf2[3];

    const int d = t & 63, part = t >> 6;
    float acc = 0.f;
    for (int k = part; k < S_; k += 4)
        acc += sc[k] * bf2f(Vg[((size_t)(b * S_ + k)) * D_ + h * 64 + d]);
    ored[t] = acc;
    __syncthreads();
    if (t < 64) {
        const float o = (ored[t] + ored[64 + t] + ored[128 + t] + ored[192 + t]) / sum;
        O[rowQ * D_ + h * 64 + t] = f2bf(o);
    }
}

// ---------------------------------------------------------------------------
// out = LayerNorm(mainp + resid) * gamma + beta.
// mainp internal bf16; resid external iff r_ext; gamma/beta external;
// out external iff o_ext (then dtype per flag), else internal bf16.
// ---------------------------------------------------------------------------
__global__ __launch_bounds__(256) void add_ln(
    const u16* __restrict__ mainp, const void* __restrict__ resid, int r_ext,
    const void* __restrict__ gamma, const void* __restrict__ beta,
    void* __restrict__ out, int o_ext, const int* __restrict__ flag)
{
    const int f32 = *flag;
    const int rf = r_ext ? f32 : 0;
    const int row = blockIdx.x;
    const size_t base = (size_t)row * D_;
    const int t = threadIdx.x;
    const int w = t >> 6, lane = t & 63;
    float v[4];
#pragma unroll
    for (int i = 0; i < 4; ++i) {
        const int c = i * 256 + t;
        v[i] = bf2f(mainp[base + c]) + ldx(resid, base + c, rf);
    }
    float s = v[0] + v[1] + v[2] + v[3];
#pragma unroll
    for (int off = 32; off >= 1; off >>= 1) s += __shfl_xor(s, off);
    __shared__ float red[8];
    if (lane == 0) red[w] = s;
    __syncthreads();
    const float mean = (red[0] + red[1] + red[2] + red[3]) * (1.0f / D_);
    float q = 0.f;
#pragma unroll
    for (int i = 0; i < 4; ++i) { const float dd = v[i] - mean; q += dd * dd; }
#pragma unroll
    for (int off = 32; off >= 1; off >>= 1) q += __shfl_xor(q, off);
    if (lane == 0) red[4 + w] = q;
    __syncthreads();
    const float var = (red[4] + red[5] + red[6] + red[7]) * (1.0f / D_);
    const float rstd = rsqrtf(var + 1e-5f);
#pragma unroll
    for (int i = 0; i < 4; ++i) {
        const int c = i * 256 + t;
        const float o = (v[i] - mean) * rstd * ldx(gamma, c, f32) + ldx(beta, c, f32);
        if (o_ext && f32) ((float*)out)[base + c] = o;
        else              ((u16*)out)[base + c] = f2bf(o);
    }
}

// ---------------------------------------------------------------------------
extern "C" void kernel_launch(void* const* d_in, const int* in_sizes, int n_in,
                              void* d_out, int out_size, void* d_ws, size_t ws_size,
                              hipStream_t stream)
{
    const void* x    = d_in[0];
    const int* mask  = (const int*)d_in[1];
    const void* WQ = d_in[2];  const void* bQ = d_in[3];
    const void* WK = d_in[4];  const void* bK = d_in[5];
    const void* WV = d_in[6];  const void* bV = d_in[7];
    const void* WY = d_in[8];  const void* bY = d_in[9];
    const void* ln1w = d_in[10]; const void* ln1b = d_in[11];
    const void* ln2w = d_in[12]; const void* ln2b = d_in[13];
    const void* W1 = d_in[14]; const void* b1 = d_in[15];
    const void* W2 = d_in[16]; const void* b2 = d_in[17];

    // Workspace (peak 48 MB + 4B flag):
    //  Qb[0,8) Kb[8,16) Vb[16,24) Yat[24,32)
    //  Yp->[0,8) (Qb dead)  hbf->[8,16) (Kb dead)
    //  G->[16,48) (Vb,Yat dead)  F->[0,8) (Yp dead after ln1)
    char* ws = (char*)d_ws;
    u16* Qb  = (u16*)(ws + 0  * MB_);
    u16* Kb  = (u16*)(ws + 8  * MB_);
    u16* Vb  = (u16*)(ws + 16 * MB_);
    u16* Yat = (u16*)(ws + 24 * MB_);
    u16* Yp  = (u16*)(ws + 0  * MB_);
    u16* hbf = (u16*)(ws + 8  * MB_);
    u16* G   = (u16*)(ws + 16 * MB_);
    u16* F   = (u16*)(ws + 0  * MB_);
    int* flag = (int*)(ws + 48 * MB_);

    sniff_dtype<<<1, 256, 0, stream>>>((const u16*)WQ, flag);

    gemm_naive<false><<<dim3(D_/64,  M_/64), 256, 0, stream>>>(x, 1, WQ, bQ, Qb, M_, D_, D_, flag);
    gemm_naive<false><<<dim3(D_/64,  M_/64), 256, 0, stream>>>(x, 1, WK, bK, Kb, M_, D_, D_, flag);
    gemm_naive<false><<<dim3(D_/64,  M_/64), 256, 0, stream>>>(x, 1, WV, bV, Vb, M_, D_, D_, flag);

    attn_naive<<<dim3(S_, B_*H_), 256, 0, stream>>>(Qb, Kb, Vb, mask, Yat);

    gemm_naive<false><<<dim3(D_/64,  M_/64), 256, 0, stream>>>(Yat, 0, WY, bY, Yp, M_, D_, D_, flag);

    add_ln<<<M_, 256, 0, stream>>>(Yp, x, 1, ln1w, ln1b, hbf, 0, flag);

    gemm_naive<true ><<<dim3(FF_/64, M_/64), 256, 0, stream>>>(hbf, 0, W1, b1, G, M_, FF_, D_, flag);
    gemm_naive<false><<<dim3(D_/64,  M_/64), 256, 0, stream>>>(G, 0, W2, b2, F, M_, D_, FF_, flag);

    add_ln<<<M_, 256, 0, stream>>>(F, hbf, 0, ln2w, ln2b, d_out, 1, flag);
}

// Round 5
// 592.209 us; speedup vs baseline: 16.6625x; 16.6625x over previous
//
#include <hip/hip_runtime.h>
#include <cstdint>
#include <cstddef>

#define B_ 2
#define S_ 2048
#define D_ 1024
#define H_ 16
#define DH_ 64
#define FF_ 4096
#define M_ (B_*S_)
#define MB_ ((size_t)1 << 20)

using u16 = unsigned short;
using short8 = __attribute__((ext_vector_type(8))) short;
using floatx4 = __attribute__((ext_vector_type(4))) float;

__device__ __forceinline__ float bf2f(u16 u) {
    return __uint_as_float(((uint32_t)u) << 16);
}
__device__ __forceinline__ u16 f2bf(float f) {
    uint32_t u = __float_as_uint(f);
    u += 0x7fffu + ((u >> 16) & 1u);   // RNE
    return (u16)(u >> 16);
}
// async global->LDS, 16B per lane; LDS dest = wave-uniform base + lane*16
__device__ __forceinline__ void async_copy16(const u16* g, u16* l) {
    __builtin_amdgcn_global_load_lds(
        (const __attribute__((address_space(1))) uint32_t*)g,
        (__attribute__((address_space(3))) uint32_t*)l, 16, 0, 0);
}

// ---------------------------------------------------------------------------
// f32 -> bf16 elementwise convert (x). n multiple of 1024.
// ---------------------------------------------------------------------------
__global__ __launch_bounds__(256) void cvt_f32_bf16(
    const float* __restrict__ in, u16* __restrict__ out, int n)
{
    const int i = (blockIdx.x * 256 + threadIdx.x) * 4;
    if (i < n) {
        const float4 v = *(const float4*)(in + i);
        out[i + 0] = f2bf(v.x);
        out[i + 1] = f2bf(v.y);
        out[i + 2] = f2bf(v.z);
        out[i + 3] = f2bf(v.w);
    }
}

// ---------------------------------------------------------------------------
// transpose+convert: in f32 (R x C) -> out bf16 (C x R)
// ---------------------------------------------------------------------------
__global__ void transpose_cvt(const float* __restrict__ in, u16* __restrict__ out,
                              int R, int C) {
    __shared__ float t[32][33];
    const int bx = blockIdx.x * 32, by = blockIdx.y * 32;
    const int tx = threadIdx.x, ty = threadIdx.y;
#pragma unroll
    for (int i = 0; i < 32; i += 8)
        t[ty + i][tx] = in[(size_t)(by + ty + i) * C + bx + tx];
    __syncthreads();
#pragma unroll
    for (int i = 0; i < 32; i += 8)
        out[(size_t)(bx + ty + i) * R + by + tx] = f2bf(t[tx][ty + i]);
}

// ---------------------------------------------------------------------------
// C(MxN) = A(MxK) @ W(KxN) + bias; A bf16 row-major, W as Wt (NxK bf16),
// bias f32. 128x128 tile, BK=32, 4 waves, mfma 16x16x32 bf16.
// ---------------------------------------------------------------------------
template<bool GELU, bool OUT_F32>
__global__ __launch_bounds__(256) void gemm_bt(
    const u16* __restrict__ A, const u16* __restrict__ Bt,
    const float* __restrict__ bias, void* __restrict__ Cout,
    int M, int N, int K)
{
    __shared__ alignas(16) u16 As[128 * 32];
    __shared__ alignas(16) u16 Bs[128 * 32];
    const int tid = threadIdx.x;
    const int w = tid >> 6, lane = tid & 63;
    const int lm = lane & 15, quad = lane >> 4;
    const int wm = w >> 1, wn = w & 1;
    const size_t m0 = (size_t)blockIdx.y * 128, n0 = (size_t)blockIdx.x * 128;

    const int rowS = w * 16 + (lane >> 2);
    const int colS = (lane & 3) * 8;
    const u16* gA = A + (m0 + rowS) * K + colS;
    const u16* gB = Bt + (n0 + rowS) * K + colS;
    u16* lA = As + w * 512;
    u16* lB = Bs + w * 512;

    floatx4 acc[4][4];
    const floatx4 z = {0.f, 0.f, 0.f, 0.f};
#pragma unroll
    for (int i = 0; i < 4; ++i)
#pragma unroll
        for (int j = 0; j < 4; ++j) acc[i][j] = z;

    for (int k0 = 0; k0 < K; k0 += 32) {
        __syncthreads();
        async_copy16(gA, lA);
        async_copy16(gA + (size_t)64 * K, lA + 2048);
        async_copy16(gB, lB);
        async_copy16(gB + (size_t)64 * K, lB + 2048);
        gA += 32; gB += 32;
        __syncthreads();

        short8 af[4], bfr[4];
#pragma unroll
        for (int t = 0; t < 4; ++t)
            af[t] = *(const short8*)&As[(wm * 64 + t * 16 + lm) * 32 + quad * 8];
#pragma unroll
        for (int t = 0; t < 4; ++t)
            bfr[t] = *(const short8*)&Bs[(wn * 64 + t * 16 + lm) * 32 + quad * 8];
#pragma unroll
        for (int i = 0; i < 4; ++i)
#pragma unroll
            for (int j = 0; j < 4; ++j)
                acc[i][j] = __builtin_amdgcn_mfma_f32_16x16x32_bf16(
                    af[i], bfr[j], acc[i][j], 0, 0, 0);
    }

#pragma unroll
    for (int i = 0; i < 4; ++i) {
        const size_t r0 = m0 + wm * 64 + i * 16 + quad * 4;
#pragma unroll
        for (int j = 0; j < 4; ++j) {
            const size_t c = n0 + wn * 64 + j * 16 + lm;
            const float bv = bias[c];
#pragma unroll
            for (int t = 0; t < 4; ++t) {
                float v = acc[i][j][t] + bv;
                if (GELU) v = 0.5f * v * (1.f + erff(v * 0.70710678118f));
                if (OUT_F32) ((float*)Cout)[(r0 + t) * (size_t)N + c] = v;
                else         ((u16*)Cout)[(r0 + t) * (size_t)N + c] = f2bf(v);
            }
        }
    }
}

// ---------------------------------------------------------------------------
// Flash attention: grid (S/64, B*H); 4 waves x 16 queries; key tiles of 64.
// ---------------------------------------------------------------------------
__global__ __launch_bounds__(256) void attn_kernel(
    const u16* __restrict__ Q, const u16* __restrict__ Kg,
    const u16* __restrict__ Vg, const int* __restrict__ mask,
    u16* __restrict__ O)
{
    __shared__ alignas(16) u16 Kt[64 * 64];
    __shared__ alignas(16) u16 Vs[64 * 64];
    __shared__ alignas(16) u16 Pw[4][16 * 64];
    const int tid = threadIdx.x, w = tid >> 6, lane = tid & 63;
    const int lm = lane & 15, quad = lane >> 4;
    const int bh = blockIdx.y, b = bh >> 4, h = bh & 15;
    const int q0 = blockIdx.x * 64;

    const u16* qp = Q + ((size_t)(b * S_ + q0 + w * 16 + lm)) * D_ + h * 64;
    const short8 aq0 = *(const short8*)(qp + quad * 8);
    const short8 aq1 = *(const short8*)(qp + 32 + quad * 8);

    const int keyS = w * 8 + (lane >> 3);
    const int dhS = (lane & 7) * 8;
    const u16* gK = Kg + ((size_t)(b * S_ + keyS)) * D_ + h * 64 + dhS;
    const u16* gV = Vg + ((size_t)(b * S_ + keyS)) * D_ + h * 64 + dhS;
    u16* lK = Kt + w * 512;
    u16* lV = Vs + w * 512;

    float mrow[4], lrow[4];
    floatx4 o[4];
    const floatx4 z = {0.f, 0.f, 0.f, 0.f};
#pragma unroll
    for (int i = 0; i < 4; ++i) { mrow[i] = -1e30f; lrow[i] = 0.f; o[i] = z; }

    const int* mp = mask + b * S_;

    for (int kt = 0; kt < S_; kt += 64) {
        __syncthreads();
        async_copy16(gK, lK);
        async_copy16(gK + (size_t)32 * D_, lK + 2048);
        async_copy16(gV, lV);
        async_copy16(gV + (size_t)32 * D_, lV + 2048);
        gK += (size_t)64 * D_; gV += (size_t)64 * D_;
        __syncthreads();

        float st[4][4];
#pragma unroll
        for (int ns = 0; ns < 4; ++ns) {
            floatx4 s = z;
            const short8 bk0 = *(const short8*)&Kt[(ns * 16 + lm) * 64 + quad * 8];
            const short8 bk1 = *(const short8*)&Kt[(ns * 16 + lm) * 64 + 32 + quad * 8];
            s = __builtin_amdgcn_mfma_f32_16x16x32_bf16(aq0, bk0, s, 0, 0, 0);
            s = __builtin_amdgcn_mfma_f32_16x16x32_bf16(aq1, bk1, s, 0, 0, 0);
            const bool mz = (mp[kt + ns * 16 + lm] == 0);
#pragma unroll
            for (int i = 0; i < 4; ++i)
                st[ns][i] = mz ? -1e30f : s[i] * 0.125f;
        }
#pragma unroll
        for (int i = 0; i < 4; ++i) {
            float tm = fmaxf(fmaxf(st[0][i], st[1][i]), fmaxf(st[2][i], st[3][i]));
#pragma unroll
            for (int off = 1; off < 16; off <<= 1) tm = fmaxf(tm, __shfl_xor(tm, off));
            const float mn = fmaxf(mrow[i], tm);
            const float alpha = __expf(mrow[i] - mn);
            mrow[i] = mn;
            float rs = 0.f;
#pragma unroll
            for (int ns = 0; ns < 4; ++ns) {
                const float p = __expf(st[ns][i] - mn);
                st[ns][i] = p; rs += p;
            }
#pragma unroll
            for (int off = 1; off < 16; off <<= 1) rs += __shfl_xor(rs, off);
            lrow[i] = lrow[i] * alpha + rs;
#pragma unroll
            for (int ds = 0; ds < 4; ++ds) o[ds][i] *= alpha;
        }
#pragma unroll
        for (int ns = 0; ns < 4; ++ns)
#pragma unroll
            for (int i = 0; i < 4; ++i)
                Pw[w][(quad * 4 + i) * 64 + ns * 16 + lm] = f2bf(st[ns][i]);
        __syncthreads();
        const short8 pf0 = *(const short8*)&Pw[w][lm * 64 + quad * 8];
        const short8 pf1 = *(const short8*)&Pw[w][lm * 64 + 32 + quad * 8];
#pragma unroll
        for (int ds = 0; ds < 4; ++ds) {
            short8 vf0, vf1;
#pragma unroll
            for (int j = 0; j < 8; ++j) {
                ((u16*)&vf0)[j] = Vs[(quad * 8 + j) * 64 + ds * 16 + lm];
                ((u16*)&vf1)[j] = Vs[(32 + quad * 8 + j) * 64 + ds * 16 + lm];
            }
            o[ds] = __builtin_amdgcn_mfma_f32_16x16x32_bf16(pf0, vf0, o[ds], 0, 0, 0);
            o[ds] = __builtin_amdgcn_mfma_f32_16x16x32_bf16(pf1, vf1, o[ds], 0, 0, 0);
        }
    }
#pragma unroll
    for (int ds = 0; ds < 4; ++ds)
#pragma unroll
        for (int i = 0; i < 4; ++i) {
            const size_t r = (size_t)(b * S_ + q0 + w * 16 + quad * 4 + i);
            O[r * D_ + h * 64 + ds * 16 + lm] = f2bf(o[ds][i] / lrow[i]);
        }
}

// ---------------------------------------------------------------------------
// out = LayerNorm(mainp + resid) * gamma + beta. gamma/beta f32.
// Dtypes per template flags. Safe for out == mainp (rows are block-disjoint;
// all reads precede writes within the block).
// ---------------------------------------------------------------------------
template<bool MAIN_F32, bool RESID_F32, bool OUT_F32>
__global__ __launch_bounds__(256) void add_ln(
    const void* __restrict__ mainp, const void* __restrict__ resid,
    const float* __restrict__ gamma, const float* __restrict__ beta,
    void* __restrict__ out)
{
    const int row = blockIdx.x;
    const size_t base = (size_t)row * D_;
    const int t = threadIdx.x;
    const int w = t >> 6, lane = t & 63;
    float v[4];
#pragma unroll
    for (int i = 0; i < 4; ++i) {
        const int c = i * 256 + t;
        const float mv = MAIN_F32 ? ((const float*)mainp)[base + c]
                                  : bf2f(((const u16*)mainp)[base + c]);
        const float rv = RESID_F32 ? ((const float*)resid)[base + c]
                                   : bf2f(((const u16*)resid)[base + c]);
        v[i] = mv + rv;
    }
    float s = v[0] + v[1] + v[2] + v[3];
#pragma unroll
    for (int off = 32; off >= 1; off >>= 1) s += __shfl_xor(s, off);
    __shared__ float red[8];
    if (lane == 0) red[w] = s;
    __syncthreads();
    const float mean = (red[0] + red[1] + red[2] + red[3]) * (1.0f / D_);
    float q = 0.f;
#pragma unroll
    for (int i = 0; i < 4; ++i) { const float dd = v[i] - mean; q += dd * dd; }
#pragma unroll
    for (int off = 32; off >= 1; off >>= 1) q += __shfl_xor(q, off);
    if (lane == 0) red[4 + w] = q;
    __syncthreads();
    const float var = (red[4] + red[5] + red[6] + red[7]) * (1.0f / D_);
    const float rstd = rsqrtf(var + 1e-5f);
#pragma unroll
    for (int i = 0; i < 4; ++i) {
        const int c = i * 256 + t;
        const float o = (v[i] - mean) * rstd * gamma[c] + beta[c];
        if (OUT_F32) ((float*)out)[base + c] = o;
        else         ((u16*)out)[base + c] = f2bf(o);
    }
}

// ---------------------------------------------------------------------------
extern "C" void kernel_launch(void* const* d_in, const int* in_sizes, int n_in,
                              void* d_out, int out_size, void* d_ws, size_t ws_size,
                              hipStream_t stream)
{
    const float* x   = (const float*)d_in[0];
    const int* mask  = (const int*)d_in[1];
    const float* WQ = (const float*)d_in[2];  const float* bQ = (const float*)d_in[3];
    const float* WK = (const float*)d_in[4];  const float* bK = (const float*)d_in[5];
    const float* WV = (const float*)d_in[6];  const float* bV = (const float*)d_in[7];
    const float* WY = (const float*)d_in[8];  const float* bY = (const float*)d_in[9];
    const float* ln1w = (const float*)d_in[10]; const float* ln1b = (const float*)d_in[11];
    const float* ln2w = (const float*)d_in[12]; const float* ln2b = (const float*)d_in[13];
    const float* W1 = (const float*)d_in[14]; const float* b1 = (const float*)d_in[15];
    const float* W2 = (const float*)d_in[16]; const float* b2 = (const float*)d_in[17];

    // Workspace (peak 48 MB, proven budget), lazy transposes enable reuse:
    //  xb[0,8) -> W1t -> W2t ; WQt[8,10) WKt[10,12) WVt[12,14) -> WYt[8,10) -> hbf[8,16)
    //  Qb[16,24) -> Yp -> G ; Kb[24,32) -> G ; Vb[32,40) -> G ; Yat[40,48) -> G
    char* ws = (char*)d_ws;
    u16* xb  = (u16*)(ws + 0  * MB_);
    u16* WQt = (u16*)(ws + 8  * MB_);
    u16* WKt = (u16*)(ws + 10 * MB_);
    u16* WVt = (u16*)(ws + 12 * MB_);
    u16* Qb  = (u16*)(ws + 16 * MB_);
    u16* Kb  = (u16*)(ws + 24 * MB_);
    u16* Vb  = (u16*)(ws + 32 * MB_);
    u16* Yat = (u16*)(ws + 40 * MB_);
    u16* WYt = (u16*)(ws + 8  * MB_);   // after WQt dead
    u16* Yp  = (u16*)(ws + 16 * MB_);   // after Qb dead
    u16* hbf = (u16*)(ws + 8  * MB_);   // after WYt/WKt/WVt dead
    u16* W1t = (u16*)(ws + 0  * MB_);   // after xb dead
    u16* G   = (u16*)(ws + 16 * MB_);   // after Yp/Kb/Vb/Yat dead
    u16* W2t = (u16*)(ws + 0  * MB_);   // after W1t dead

    const dim3 tb(32, 8);

    cvt_f32_bf16<<<(M_*D_)/1024, 256, 0, stream>>>(x, xb, M_*D_);
    transpose_cvt<<<dim3(D_/32, D_/32), tb, 0, stream>>>(WQ, WQt, D_, D_);
    transpose_cvt<<<dim3(D_/32, D_/32), tb, 0, stream>>>(WK, WKt, D_, D_);
    transpose_cvt<<<dim3(D_/32, D_/32), tb, 0, stream>>>(WV, WVt, D_, D_);

    gemm_bt<false,false><<<dim3(D_/128, M_/128), 256, 0, stream>>>(xb, WQt, bQ, Qb, M_, D_, D_);
    gemm_bt<false,false><<<dim3(D_/128, M_/128), 256, 0, stream>>>(xb, WKt, bK, Kb, M_, D_, D_);
    gemm_bt<false,false><<<dim3(D_/128, M_/128), 256, 0, stream>>>(xb, WVt, bV, Vb, M_, D_, D_);

    attn_kernel<<<dim3(S_/64, B_*H_), 256, 0, stream>>>(Qb, Kb, Vb, mask, Yat);

    transpose_cvt<<<dim3(D_/32, D_/32), tb, 0, stream>>>(WY, WYt, D_, D_);
    gemm_bt<false,false><<<dim3(D_/128, M_/128), 256, 0, stream>>>(Yat, WYt, bY, Yp, M_, D_, D_);

    add_ln<false,true,false><<<M_, 256, 0, stream>>>(Yp, x, ln1w, ln1b, hbf);

    transpose_cvt<<<dim3(FF_/32, D_/32), tb, 0, stream>>>(W1, W1t, D_, FF_);
    gemm_bt<true,false><<<dim3(FF_/128, M_/128), 256, 0, stream>>>(hbf, W1t, b1, G, M_, FF_, D_);

    transpose_cvt<<<dim3(D_/32, FF_/32), tb, 0, stream>>>(W2, W2t, FF_, D_);
    gemm_bt<false,true><<<dim3(D_/128, M_/128), 256, 0, stream>>>(G, W2t, b2, (float*)d_out, M_, D_, FF_);

    add_ln<true,false,true><<<M_, 256, 0, stream>>>((float*)d_out, hbf, ln2w, ln2b, d_out);
}

// Round 6
// 534.983 us; speedup vs baseline: 18.4449x; 1.1070x over previous
//
#include <hip/hip_runtime.h>
#include <cstdint>
#include <cstddef>

#define B_ 2
#define S_ 2048
#define D_ 1024
#define H_ 16
#define DH_ 64
#define FF_ 4096
#define M_ (B_*S_)
#define MB_ ((size_t)1 << 20)

using u16 = unsigned short;
using short8 = __attribute__((ext_vector_type(8))) short;
using floatx4 = __attribute__((ext_vector_type(4))) float;

__device__ __forceinline__ float bf2f(u16 u) {
    return __uint_as_float(((uint32_t)u) << 16);
}
__device__ __forceinline__ u16 f2bf(float f) {
    uint32_t u = __float_as_uint(f);
    u += 0x7fffu + ((u >> 16) & 1u);   // RNE
    return (u16)(u >> 16);
}
// async global->LDS, 16B per lane; LDS dest = wave-uniform base + lane*16
__device__ __forceinline__ void async_copy16(const u16* g, u16* l) {
    __builtin_amdgcn_global_load_lds(
        (const __attribute__((address_space(1))) uint32_t*)g,
        (__attribute__((address_space(3))) uint32_t*)l, 16, 0, 0);
}

// ---------------------------------------------------------------------------
// f32 -> bf16 elementwise convert (x). n multiple of 1024.
// ---------------------------------------------------------------------------
__global__ __launch_bounds__(256) void cvt_f32_bf16(
    const float* __restrict__ in, u16* __restrict__ out, int n)
{
    const int i = (blockIdx.x * 256 + threadIdx.x) * 4;
    if (i < n) {
        const float4 v = *(const float4*)(in + i);
        out[i + 0] = f2bf(v.x);
        out[i + 1] = f2bf(v.y);
        out[i + 2] = f2bf(v.z);
        out[i + 3] = f2bf(v.w);
    }
}

// ---------------------------------------------------------------------------
// transpose+convert: in f32 (R x C) -> out bf16 (C x R)
// ---------------------------------------------------------------------------
__global__ void transpose_cvt(const float* __restrict__ in, u16* __restrict__ out,
                              int R, int C) {
    __shared__ float t[32][33];
    const int bx = blockIdx.x * 32, by = blockIdx.y * 32;
    const int tx = threadIdx.x, ty = threadIdx.y;
#pragma unroll
    for (int i = 0; i < 32; i += 8)
        t[ty + i][tx] = in[(size_t)(by + ty + i) * C + bx + tx];
    __syncthreads();
#pragma unroll
    for (int i = 0; i < 32; i += 8)
        out[(size_t)(bx + ty + i) * R + by + tx] = f2bf(t[tx][ty + i]);
}

// ---------------------------------------------------------------------------
// Generic GEMM: C(MxN) = A(MxK) @ W + bias; W as Wt (NxK bf16), bias f32.
// 128x128 tile, BK=32, 4 waves, mfma 16x16x32 bf16.
// ---------------------------------------------------------------------------
template<bool GELU, bool OUT_F32>
__global__ __launch_bounds__(256) void gemm_bt(
    const u16* __restrict__ A, const u16* __restrict__ Bt,
    const float* __restrict__ bias, void* __restrict__ Cout,
    int M, int N, int K)
{
    __shared__ alignas(16) u16 As[128 * 32];
    __shared__ alignas(16) u16 Bs[128 * 32];
    const int tid = threadIdx.x;
    const int w = tid >> 6, lane = tid & 63;
    const int lm = lane & 15, quad = lane >> 4;
    const int wm = w >> 1, wn = w & 1;
    const size_t m0 = (size_t)blockIdx.y * 128, n0 = (size_t)blockIdx.x * 128;

    const int rowS = w * 16 + (lane >> 2);
    const int colS = (lane & 3) * 8;
    const u16* gA = A + (m0 + rowS) * K + colS;
    const u16* gB = Bt + (n0 + rowS) * K + colS;
    u16* lA = As + w * 512;
    u16* lB = Bs + w * 512;

    floatx4 acc[4][4];
    const floatx4 z = {0.f, 0.f, 0.f, 0.f};
#pragma unroll
    for (int i = 0; i < 4; ++i)
#pragma unroll
        for (int j = 0; j < 4; ++j) acc[i][j] = z;

    for (int k0 = 0; k0 < K; k0 += 32) {
        __syncthreads();
        async_copy16(gA, lA);
        async_copy16(gA + (size_t)64 * K, lA + 2048);
        async_copy16(gB, lB);
        async_copy16(gB + (size_t)64 * K, lB + 2048);
        gA += 32; gB += 32;
        __syncthreads();

        short8 af[4], bfr[4];
#pragma unroll
        for (int t = 0; t < 4; ++t)
            af[t] = *(const short8*)&As[(wm * 64 + t * 16 + lm) * 32 + quad * 8];
#pragma unroll
        for (int t = 0; t < 4; ++t)
            bfr[t] = *(const short8*)&Bs[(wn * 64 + t * 16 + lm) * 32 + quad * 8];
#pragma unroll
        for (int i = 0; i < 4; ++i)
#pragma unroll
            for (int j = 0; j < 4; ++j)
                acc[i][j] = __builtin_amdgcn_mfma_f32_16x16x32_bf16(
                    af[i], bfr[j], acc[i][j], 0, 0, 0);
    }

#pragma unroll
    for (int i = 0; i < 4; ++i) {
        const size_t r0 = m0 + wm * 64 + i * 16 + quad * 4;
#pragma unroll
        for (int j = 0; j < 4; ++j) {
            const size_t c = n0 + wn * 64 + j * 16 + lm;
            const float bv = bias[c];
#pragma unroll
            for (int t = 0; t < 4; ++t) {
                float v = acc[i][j][t] + bv;
                if (GELU) v = 0.5f * v * (1.f + erff(v * 0.70710678118f));
                if (OUT_F32) ((float*)Cout)[(r0 + t) * (size_t)N + c] = v;
                else         ((u16*)Cout)[(r0 + t) * (size_t)N + c] = f2bf(v);
            }
        }
    }
}

// ---------------------------------------------------------------------------
// Fused QKV GEMM: A(M x 1024) @ Wqkv (1024 x 3072), Wqkvt rows: [WQ^T;WK^T;WV^T].
// Q,K written [m][1024]; V written transposed per head: Vt[((b*16+h)*64+dh)*S + s].
// ---------------------------------------------------------------------------
__global__ __launch_bounds__(256) void gemm_qkv(
    const u16* __restrict__ A, const u16* __restrict__ Bt,
    const float* __restrict__ bQ, const float* __restrict__ bK,
    const float* __restrict__ bV,
    u16* __restrict__ Qb, u16* __restrict__ Kb, u16* __restrict__ Vt)
{
    const int K = D_, N = 3 * D_;
    __shared__ alignas(16) u16 As[128 * 32];
    __shared__ alignas(16) u16 Bs[128 * 32];
    const int tid = threadIdx.x;
    const int w = tid >> 6, lane = tid & 63;
    const int lm = lane & 15, quad = lane >> 4;
    const int wm = w >> 1, wn = w & 1;
    const size_t m0 = (size_t)blockIdx.y * 128, n0 = (size_t)blockIdx.x * 128;

    const int rowS = w * 16 + (lane >> 2);
    const int colS = (lane & 3) * 8;
    const u16* gA = A + (m0 + rowS) * K + colS;
    const u16* gB = Bt + (n0 + rowS) * K + colS;
    u16* lA = As + w * 512;
    u16* lB = Bs + w * 512;

    floatx4 acc[4][4];
    const floatx4 z = {0.f, 0.f, 0.f, 0.f};
#pragma unroll
    for (int i = 0; i < 4; ++i)
#pragma unroll
        for (int j = 0; j < 4; ++j) acc[i][j] = z;

    for (int k0 = 0; k0 < K; k0 += 32) {
        __syncthreads();
        async_copy16(gA, lA);
        async_copy16(gA + (size_t)64 * K, lA + 2048);
        async_copy16(gB, lB);
        async_copy16(gB + (size_t)64 * K, lB + 2048);
        gA += 32; gB += 32;
        __syncthreads();

        short8 af[4], bfr[4];
#pragma unroll
        for (int t = 0; t < 4; ++t)
            af[t] = *(const short8*)&As[(wm * 64 + t * 16 + lm) * 32 + quad * 8];
#pragma unroll
        for (int t = 0; t < 4; ++t)
            bfr[t] = *(const short8*)&Bs[(wn * 64 + t * 16 + lm) * 32 + quad * 8];
#pragma unroll
        for (int i = 0; i < 4; ++i)
#pragma unroll
            for (int j = 0; j < 4; ++j)
                acc[i][j] = __builtin_amdgcn_mfma_f32_16x16x32_bf16(
                    af[i], bfr[j], acc[i][j], 0, 0, 0);
    }

#pragma unroll
    for (int i = 0; i < 4; ++i) {
        const size_t r0 = m0 + wm * 64 + i * 16 + quad * 4;
#pragma unroll
        for (int j = 0; j < 4; ++j) {
            const size_t c = n0 + wn * 64 + j * 16 + lm;
            const int sel = (int)(c >> 10);       // 0=Q 1=K 2=V (uniform per j)
            const int col = (int)(c & 1023);
            const float bv = sel == 0 ? bQ[col] : (sel == 1 ? bK[col] : bV[col]);
#pragma unroll
            for (int t = 0; t < 4; ++t) {
                const size_t r = r0 + t;
                const u16 v = f2bf(acc[i][j][t] + bv);
                if (sel == 0)      Qb[r * (size_t)D_ + col] = v;
                else if (sel == 1) Kb[r * (size_t)D_ + col] = v;
                else {
                    const int h = col >> 6, dh = col & 63;
                    const int bb = (int)(r >> 11), s = (int)(r & 2047);
                    Vt[((size_t)((bb * 16 + h) * 64 + dh)) * S_ + s] = v;
                }
            }
        }
    }
}

// ---------------------------------------------------------------------------
// Flash attention: grid (S/64, B*H); 4 waves x 16 queries; key tiles of 64.
// K staged [key][dh], V (pre-transposed in global) staged [dh][key]; both with
// stride 72 u16 (144 B -> 4-bank rotation -> 2 lanes/bank, conflict-free).
// ---------------------------------------------------------------------------
__global__ __launch_bounds__(256) void attn_kernel(
    const u16* __restrict__ Q, const u16* __restrict__ Kg,
    const u16* __restrict__ Vt, const int* __restrict__ mask,
    u16* __restrict__ O)
{
    __shared__ alignas(16) u16 Kt[64 * 72];
    __shared__ alignas(16) u16 Vs[64 * 72];     // [dh][key]
    __shared__ alignas(16) u16 Pw[4][16 * 72];
    const int tid = threadIdx.x, w = tid >> 6, lane = tid & 63;
    const int lm = lane & 15, quad = lane >> 4;
    const int b = blockIdx.y >> 4, h = blockIdx.y & 15;
    const int q0 = blockIdx.x * 64;

    // Q A-frags: m = lane&15 -> query, k = quad*8+j -> dh
    const u16* qp = Q + ((size_t)(b * S_ + q0 + w * 16 + lm)) * D_ + h * 64;
    const short8 aq0 = *(const short8*)(qp + quad * 8);
    const short8 aq1 = *(const short8*)(qp + 32 + quad * 8);

    // staging: thread covers row tid>>2 (0..63), 16 u16 at col (tid&3)*16
    const int sRow = tid >> 2, sCol = (tid & 3) * 16;
    const u16* gK = Kg + ((size_t)(b * S_ + sRow)) * D_ + h * 64 + sCol;
    const u16* gV = Vt + ((size_t)((b * 16 + h) * 64 + sRow)) * S_ + sCol;

    float mrow[4], lrow[4];
    floatx4 o[4];
    const floatx4 z = {0.f, 0.f, 0.f, 0.f};
#pragma unroll
    for (int i = 0; i < 4; ++i) { mrow[i] = -1e30f; lrow[i] = 0.f; o[i] = z; }

    const int* mp = mask + b * S_;

    for (int kt = 0; kt < S_; kt += 64) {
        __syncthreads();
        *(short8*)&Kt[sRow * 72 + sCol]     = *(const short8*)(gK);
        *(short8*)&Kt[sRow * 72 + sCol + 8] = *(const short8*)(gK + 8);
        *(short8*)&Vs[sRow * 72 + sCol]     = *(const short8*)(gV);
        *(short8*)&Vs[sRow * 72 + sCol + 8] = *(const short8*)(gV + 8);
        gK += (size_t)64 * D_; gV += 64;
        __syncthreads();

        // scores: S(16q x 64k); B[k=dh][n=key] = Kt[key*72 + dh]
        float st[4][4];
#pragma unroll
        for (int ns = 0; ns < 4; ++ns) {
            floatx4 s = z;
            const short8 bk0 = *(const short8*)&Kt[(ns * 16 + lm) * 72 + quad * 8];
            const short8 bk1 = *(const short8*)&Kt[(ns * 16 + lm) * 72 + 32 + quad * 8];
            s = __builtin_amdgcn_mfma_f32_16x16x32_bf16(aq0, bk0, s, 0, 0, 0);
            s = __builtin_amdgcn_mfma_f32_16x16x32_bf16(aq1, bk1, s, 0, 0, 0);
            const bool mz = (mp[kt + ns * 16 + lm] == 0);
#pragma unroll
            for (int i = 0; i < 4; ++i)
                st[ns][i] = mz ? -1e30f : s[i] * 0.125f;
        }
        // online softmax per row (row = quad*4+i; reduce over 16 lanes)
#pragma unroll
        for (int i = 0; i < 4; ++i) {
            float tm = fmaxf(fmaxf(st[0][i], st[1][i]), fmaxf(st[2][i], st[3][i]));
#pragma unroll
            for (int off = 1; off < 16; off <<= 1) tm = fmaxf(tm, __shfl_xor(tm, off));
            const float mn = fmaxf(mrow[i], tm);
            const float alpha = __expf(mrow[i] - mn);
            mrow[i] = mn;
            float rs = 0.f;
#pragma unroll
            for (int ns = 0; ns < 4; ++ns) {
                const float p = __expf(st[ns][i] - mn);
                st[ns][i] = p; rs += p;
            }
#pragma unroll
            for (int off = 1; off < 16; off <<= 1) rs += __shfl_xor(rs, off);
            lrow[i] = lrow[i] * alpha + rs;
#pragma unroll
            for (int ds = 0; ds < 4; ++ds) o[ds][i] *= alpha;
        }
        // P: C-layout -> LDS -> A-layout
#pragma unroll
        for (int ns = 0; ns < 4; ++ns)
#pragma unroll
            for (int i = 0; i < 4; ++i)
                Pw[w][(quad * 4 + i) * 72 + ns * 16 + lm] = f2bf(st[ns][i]);
        __syncthreads();
        const short8 pf0 = *(const short8*)&Pw[w][lm * 72 + quad * 8];
        const short8 pf1 = *(const short8*)&Pw[w][lm * 72 + 32 + quad * 8];
        // PV: B[k=key][n=dh] = Vs[dh*72 + key] -> contiguous b128 reads
#pragma unroll
        for (int ds = 0; ds < 4; ++ds) {
            const short8 vf0 = *(const short8*)&Vs[(ds * 16 + lm) * 72 + quad * 8];
            const short8 vf1 = *(const short8*)&Vs[(ds * 16 + lm) * 72 + 32 + quad * 8];
            o[ds] = __builtin_amdgcn_mfma_f32_16x16x32_bf16(pf0, vf0, o[ds], 0, 0, 0);
            o[ds] = __builtin_amdgcn_mfma_f32_16x16x32_bf16(pf1, vf1, o[ds], 0, 0, 0);
        }
    }
#pragma unroll
    for (int ds = 0; ds < 4; ++ds)
#pragma unroll
        for (int i = 0; i < 4; ++i) {
            const size_t r = (size_t)(b * S_ + q0 + w * 16 + quad * 4 + i);
            O[r * D_ + h * 64 + ds * 16 + lm] = f2bf(o[ds][i] / lrow[i]);
        }
}

// ---------------------------------------------------------------------------
// out = LayerNorm(mainp + resid) * gamma + beta. gamma/beta f32.
// Safe for out == mainp (rows are block-disjoint; reads precede writes).
// ---------------------------------------------------------------------------
template<bool MAIN_F32, bool RESID_F32, bool OUT_F32>
__global__ __launch_bounds__(256) void add_ln(
    const void* __restrict__ mainp, const void* __restrict__ resid,
    const float* __restrict__ gamma, const float* __restrict__ beta,
    void* __restrict__ out)
{
    const int row = blockIdx.x;
    const size_t base = (size_t)row * D_;
    const int t = threadIdx.x;
    const int w = t >> 6, lane = t & 63;
    float v[4];
#pragma unroll
    for (int i = 0; i < 4; ++i) {
        const int c = i * 256 + t;
        const float mv = MAIN_F32 ? ((const float*)mainp)[base + c]
                                  : bf2f(((const u16*)mainp)[base + c]);
        const float rv = RESID_F32 ? ((const float*)resid)[base + c]
                                   : bf2f(((const u16*)resid)[base + c]);
        v[i] = mv + rv;
    }
    float s = v[0] + v[1] + v[2] + v[3];
#pragma unroll
    for (int off = 32; off >= 1; off >>= 1) s += __shfl_xor(s, off);
    __shared__ float red[8];
    if (lane == 0) red[w] = s;
    __syncthreads();
    const float mean = (red[0] + red[1] + red[2] + red[3]) * (1.0f / D_);
    float q = 0.f;
#pragma unroll
    for (int i = 0; i < 4; ++i) { const float dd = v[i] - mean; q += dd * dd; }
#pragma unroll
    for (int off = 32; off >= 1; off >>= 1) q += __shfl_xor(q, off);
    if (lane == 0) red[4 + w] = q;
    __syncthreads();
    const float var = (red[4] + red[5] + red[6] + red[7]) * (1.0f / D_);
    const float rstd = rsqrtf(var + 1e-5f);
#pragma unroll
    for (int i = 0; i < 4; ++i) {
        const int c = i * 256 + t;
        const float o = (v[i] - mean) * rstd * gamma[c] + beta[c];
        if (OUT_F32) ((float*)out)[base + c] = o;
        else         ((u16*)out)[base + c] = f2bf(o);
    }
}

// ---------------------------------------------------------------------------
extern "C" void kernel_launch(void* const* d_in, const int* in_sizes, int n_in,
                              void* d_out, int out_size, void* d_ws, size_t ws_size,
                              hipStream_t stream)
{
    const float* x   = (const float*)d_in[0];
    const int* mask  = (const int*)d_in[1];
    const float* WQ = (const float*)d_in[2];  const float* bQ = (const float*)d_in[3];
    const float* WK = (const float*)d_in[4];  const float* bK = (const float*)d_in[5];
    const float* WV = (const float*)d_in[6];  const float* bV = (const float*)d_in[7];
    const float* WY = (const float*)d_in[8];  const float* bY = (const float*)d_in[9];
    const float* ln1w = (const float*)d_in[10]; const float* ln1b = (const float*)d_in[11];
    const float* ln2w = (const float*)d_in[12]; const float* ln2b = (const float*)d_in[13];
    const float* W1 = (const float*)d_in[14]; const float* b1 = (const float*)d_in[15];
    const float* W2 = (const float*)d_in[16]; const float* b2 = (const float*)d_in[17];

    // Workspace (peak 48 MB):
    //  xb[0,8) -> W1t -> W2t ; Wqkvt[8,14) -> WYt[8,10) -> hbf[8,16)
    //  Qb[16,24) -> Yp -> G ; Kb[24,32) -> G ; Vt[32,40) -> G ; Yat[40,48) -> G
    char* ws = (char*)d_ws;
    u16* xb    = (u16*)(ws + 0  * MB_);
    u16* Wqkvt = (u16*)(ws + 8  * MB_);        // 6 MB: [WQ^T; WK^T; WV^T]
    u16* Qb    = (u16*)(ws + 16 * MB_);
    u16* Kb    = (u16*)(ws + 24 * MB_);
    u16* Vt    = (u16*)(ws + 32 * MB_);        // [b][h][dh][s]
    u16* Yat   = (u16*)(ws + 40 * MB_);
    u16* WYt   = (u16*)(ws + 8  * MB_);        // after Wqkvt dead
    u16* Yp    = (u16*)(ws + 16 * MB_);        // after Qb dead
    u16* hbf   = (u16*)(ws + 8  * MB_);        // after WYt dead
    u16* W1t   = (u16*)(ws + 0  * MB_);        // after xb dead
    u16* G     = (u16*)(ws + 16 * MB_);        // after Yp/Kb/Vt/Yat dead
    u16* W2t   = (u16*)(ws + 0  * MB_);        // after W1t dead

    const dim3 tb(32, 8);

    cvt_f32_bf16<<<(M_*D_)/1024, 256, 0, stream>>>(x, xb, M_*D_);
    transpose_cvt<<<dim3(D_/32, D_/32), tb, 0, stream>>>(WQ, Wqkvt,                 D_, D_);
    transpose_cvt<<<dim3(D_/32, D_/32), tb, 0, stream>>>(WK, Wqkvt + (size_t)D_*D_, D_, D_);
    transpose_cvt<<<dim3(D_/32, D_/32), tb, 0, stream>>>(WV, Wqkvt + (size_t)2*D_*D_, D_, D_);

    gemm_qkv<<<dim3(3*D_/128, M_/128), 256, 0, stream>>>(xb, Wqkvt, bQ, bK, bV, Qb, Kb, Vt);

    attn_kernel<<<dim3(S_/64, B_*H_), 256, 0, stream>>>(Qb, Kb, Vt, mask, Yat);

    transpose_cvt<<<dim3(D_/32, D_/32), tb, 0, stream>>>(WY, WYt, D_, D_);
    gemm_bt<false,false><<<dim3(D_/128, M_/128), 256, 0, stream>>>(Yat, WYt, bY, Yp, M_, D_, D_);

    add_ln<false,true,false><<<M_, 256, 0, stream>>>(Yp, x, ln1w, ln1b, hbf);

    transpose_cvt<<<dim3(FF_/32, D_/32), tb, 0, stream>>>(W1, W1t, D_, FF_);
    gemm_bt<true,false><<<dim3(FF_/128, M_/128), 256, 0, stream>>>(hbf, W1t, b1, G, M_, FF_, D_);

    transpose_cvt<<<dim3(D_/32, FF_/32), tb, 0, stream>>>(W2, W2t, FF_, D_);
    gemm_bt<false,true><<<dim3(D_/128, M_/128), 256, 0, stream>>>(G, W2t, b2, (float*)d_out, M_, D_, FF_);

    add_ln<true,false,true><<<M_, 256, 0, stream>>>((float*)d_out, hbf, ln2w, ln2b, d_out);
}

// Round 7
// 507.055 us; speedup vs baseline: 19.4608x; 1.0551x over previous
//
#include <hip/hip_runtime.h>
#include <cstdint>
#include <cstddef>

#define B_ 2
#define S_ 2048
#define D_ 1024
#define H_ 16
#define DH_ 64
#define FF_ 4096
#define M_ (B_*S_)
#define MB_ ((size_t)1 << 20)

using u16 = unsigned short;
using short8 = __attribute__((ext_vector_type(8))) short;
using short4v = __attribute__((ext_vector_type(4))) short;
using floatx4 = __attribute__((ext_vector_type(4))) float;

__device__ __forceinline__ float bf2f(u16 u) {
    return __uint_as_float(((uint32_t)u) << 16);
}
__device__ __forceinline__ u16 f2bf(float f) {
    uint32_t u = __float_as_uint(f);
    u += 0x7fffu + ((u >> 16) & 1u);   // RNE
    return (u16)(u >> 16);
}
// async global->LDS, 16B per lane; LDS dest = wave-uniform base + lane*16
__device__ __forceinline__ void async_copy16(const u16* g, u16* l) {
    __builtin_amdgcn_global_load_lds(
        (const __attribute__((address_space(1))) uint32_t*)g,
        (__attribute__((address_space(3))) uint32_t*)l, 16, 0, 0);
}

// ---------------------------------------------------------------------------
// f32 -> bf16 elementwise convert (x). n multiple of 1024.
// ---------------------------------------------------------------------------
__global__ __launch_bounds__(256) void cvt_f32_bf16(
    const float* __restrict__ in, u16* __restrict__ out, int n)
{
    const int i = (blockIdx.x * 256 + threadIdx.x) * 4;
    if (i < n) {
        const float4 v = *(const float4*)(in + i);
        out[i + 0] = f2bf(v.x);
        out[i + 1] = f2bf(v.y);
        out[i + 2] = f2bf(v.z);
        out[i + 3] = f2bf(v.w);
    }
}

// ---------------------------------------------------------------------------
// mask (int32) -> additive f32 bias: 0 or -1e30
// ---------------------------------------------------------------------------
__global__ __launch_bounds__(256) void mask_bias(
    const int* __restrict__ mask, float* __restrict__ bias, int n)
{
    const int i = blockIdx.x * 256 + threadIdx.x;
    if (i < n) bias[i] = mask[i] ? 0.f : -1e30f;
}

// ---------------------------------------------------------------------------
// transpose+convert: in f32 (R x C) -> out bf16 (C x R)
// ---------------------------------------------------------------------------
__global__ void transpose_cvt(const float* __restrict__ in, u16* __restrict__ out,
                              int R, int C) {
    __shared__ float t[32][33];
    const int bx = blockIdx.x * 32, by = blockIdx.y * 32;
    const int tx = threadIdx.x, ty = threadIdx.y;
#pragma unroll
    for (int i = 0; i < 32; i += 8)
        t[ty + i][tx] = in[(size_t)(by + ty + i) * C + bx + tx];
    __syncthreads();
#pragma unroll
    for (int i = 0; i < 32; i += 8)
        out[(size_t)(bx + ty + i) * R + by + tx] = f2bf(t[tx][ty + i]);
}

// ---------------------------------------------------------------------------
// Generic GEMM: C(MxN) = A(MxK) @ W + bias; W as Wt (NxK bf16), bias f32.
// 128x128 tile, BK=32, 4 waves, mfma 16x16x32 bf16.
// ---------------------------------------------------------------------------
template<bool GELU, bool OUT_F32>
__global__ __launch_bounds__(256) void gemm_bt(
    const u16* __restrict__ A, const u16* __restrict__ Bt,
    const float* __restrict__ bias, void* __restrict__ Cout,
    int M, int N, int K)
{
    __shared__ alignas(16) u16 As[128 * 32];
    __shared__ alignas(16) u16 Bs[128 * 32];
    const int tid = threadIdx.x;
    const int w = tid >> 6, lane = tid & 63;
    const int lm = lane & 15, quad = lane >> 4;
    const int wm = w >> 1, wn = w & 1;
    const size_t m0 = (size_t)blockIdx.y * 128, n0 = (size_t)blockIdx.x * 128;

    const int rowS = w * 16 + (lane >> 2);
    const int colS = (lane & 3) * 8;
    const u16* gA = A + (m0 + rowS) * K + colS;
    const u16* gB = Bt + (n0 + rowS) * K + colS;
    u16* lA = As + w * 512;
    u16* lB = Bs + w * 512;

    floatx4 acc[4][4];
    const floatx4 z = {0.f, 0.f, 0.f, 0.f};
#pragma unroll
    for (int i = 0; i < 4; ++i)
#pragma unroll
        for (int j = 0; j < 4; ++j) acc[i][j] = z;

    for (int k0 = 0; k0 < K; k0 += 32) {
        __syncthreads();
        async_copy16(gA, lA);
        async_copy16(gA + (size_t)64 * K, lA + 2048);
        async_copy16(gB, lB);
        async_copy16(gB + (size_t)64 * K, lB + 2048);
        gA += 32; gB += 32;
        __syncthreads();

        short8 af[4], bfr[4];
#pragma unroll
        for (int t = 0; t < 4; ++t)
            af[t] = *(const short8*)&As[(wm * 64 + t * 16 + lm) * 32 + quad * 8];
#pragma unroll
        for (int t = 0; t < 4; ++t)
            bfr[t] = *(const short8*)&Bs[(wn * 64 + t * 16 + lm) * 32 + quad * 8];
#pragma unroll
        for (int i = 0; i < 4; ++i)
#pragma unroll
            for (int j = 0; j < 4; ++j)
                acc[i][j] = __builtin_amdgcn_mfma_f32_16x16x32_bf16(
                    af[i], bfr[j], acc[i][j], 0, 0, 0);
    }

#pragma unroll
    for (int i = 0; i < 4; ++i) {
        const size_t r0 = m0 + wm * 64 + i * 16 + quad * 4;
#pragma unroll
        for (int j = 0; j < 4; ++j) {
            const size_t c = n0 + wn * 64 + j * 16 + lm;
            const float bv = bias[c];
#pragma unroll
            for (int t = 0; t < 4; ++t) {
                float v = acc[i][j][t] + bv;
                if (GELU) v = 0.5f * v * (1.f + erff(v * 0.70710678118f));
                if (OUT_F32) ((float*)Cout)[(r0 + t) * (size_t)N + c] = v;
                else         ((u16*)Cout)[(r0 + t) * (size_t)N + c] = f2bf(v);
            }
        }
    }
}

// ---------------------------------------------------------------------------
// Fused QKV GEMM: A(M x 1024) @ Wqkv (1024 x 3072), Wqkvt rows: [WQ^T;WK^T;WV^T].
// Q,K written [m][1024]; V written transposed per head: Vt[((b*16+h)*64+dh)*S + s].
// ---------------------------------------------------------------------------
__global__ __launch_bounds__(256) void gemm_qkv(
    const u16* __restrict__ A, const u16* __restrict__ Bt,
    const float* __restrict__ bQ, const float* __restrict__ bK,
    const float* __restrict__ bV,
    u16* __restrict__ Qb, u16* __restrict__ Kb, u16* __restrict__ Vt)
{
    const int K = D_, N = 3 * D_;
    __shared__ alignas(16) u16 As[128 * 32];
    __shared__ alignas(16) u16 Bs[128 * 32];
    const int tid = threadIdx.x;
    const int w = tid >> 6, lane = tid & 63;
    const int lm = lane & 15, quad = lane >> 4;
    const int wm = w >> 1, wn = w & 1;
    const size_t m0 = (size_t)blockIdx.y * 128, n0 = (size_t)blockIdx.x * 128;

    const int rowS = w * 16 + (lane >> 2);
    const int colS = (lane & 3) * 8;
    const u16* gA = A + (m0 + rowS) * K + colS;
    const u16* gB = Bt + (n0 + rowS) * K + colS;
    u16* lA = As + w * 512;
    u16* lB = Bs + w * 512;

    floatx4 acc[4][4];
    const floatx4 z = {0.f, 0.f, 0.f, 0.f};
#pragma unroll
    for (int i = 0; i < 4; ++i)
#pragma unroll
        for (int j = 0; j < 4; ++j) acc[i][j] = z;

    for (int k0 = 0; k0 < K; k0 += 32) {
        __syncthreads();
        async_copy16(gA, lA);
        async_copy16(gA + (size_t)64 * K, lA + 2048);
        async_copy16(gB, lB);
        async_copy16(gB + (size_t)64 * K, lB + 2048);
        gA += 32; gB += 32;
        __syncthreads();

        short8 af[4], bfr[4];
#pragma unroll
        for (int t = 0; t < 4; ++t)
            af[t] = *(const short8*)&As[(wm * 64 + t * 16 + lm) * 32 + quad * 8];
#pragma unroll
        for (int t = 0; t < 4; ++t)
            bfr[t] = *(const short8*)&Bs[(wn * 64 + t * 16 + lm) * 32 + quad * 8];
#pragma unroll
        for (int i = 0; i < 4; ++i)
#pragma unroll
            for (int j = 0; j < 4; ++j)
                acc[i][j] = __builtin_amdgcn_mfma_f32_16x16x32_bf16(
                    af[i], bfr[j], acc[i][j], 0, 0, 0);
    }

#pragma unroll
    for (int i = 0; i < 4; ++i) {
        const size_t r0 = m0 + wm * 64 + i * 16 + quad * 4;
#pragma unroll
        for (int j = 0; j < 4; ++j) {
            const size_t c = n0 + wn * 64 + j * 16 + lm;
            const int sel = (int)(c >> 10);       // 0=Q 1=K 2=V (uniform per j)
            const int col = (int)(c & 1023);
            const float bv = sel == 0 ? bQ[col] : (sel == 1 ? bK[col] : bV[col]);
#pragma unroll
            for (int t = 0; t < 4; ++t) {
                const size_t r = r0 + t;
                const u16 v = f2bf(acc[i][j][t] + bv);
                if (sel == 0)      Qb[r * (size_t)D_ + col] = v;
                else if (sel == 1) Kb[r * (size_t)D_ + col] = v;
                else {
                    const int h = col >> 6, dh = col & 63;
                    const int bb = (int)(r >> 11), s = (int)(r & 2047);
                    Vt[((size_t)((bb * 16 + h) * 64 + dh)) * S_ + s] = v;
                }
            }
        }
    }
}

// ---------------------------------------------------------------------------
// Flash attention, S^T formulation: grid (S/64, B*H); 4 waves x 16 queries.
// S^T = K·Q^T (operand-swapped mfma) -> C layout [key=quad*4+reg][query=lm],
// which IS the B-operand layout of mfma_16x16x16 (k=quad*4+j, n=lm). PV is
// computed as O^T += V^T·P^T fully in-register — no P LDS round-trip.
// ---------------------------------------------------------------------------
__global__ __launch_bounds__(256) void attn_kernel(
    const u16* __restrict__ Q, const u16* __restrict__ Kg,
    const u16* __restrict__ Vt, const float* __restrict__ mbias,
    u16* __restrict__ O)
{
    __shared__ alignas(16) u16 Kt[64 * 72];
    __shared__ alignas(16) u16 Vs[64 * 72];     // [dh][key]
    const int tid = threadIdx.x, w = tid >> 6, lane = tid & 63;
    const int lm = lane & 15, quad = lane >> 4;
    const int b = blockIdx.y >> 4, h = blockIdx.y & 15;
    const int q0 = blockIdx.x * 64;

    // Q B-frag: n = lane&15 -> query, k = quad*8+j -> dh
    const u16* qp = Q + ((size_t)(b * S_ + q0 + w * 16 + lm)) * D_ + h * 64;
    const short8 bq0 = *(const short8*)(qp + quad * 8);
    const short8 bq1 = *(const short8*)(qp + 32 + quad * 8);

    // staging: thread covers row tid>>2 (0..63), 16 u16 at col (tid&3)*16
    const int sRow = tid >> 2, sCol = (tid & 3) * 16;
    const u16* gK = Kg + ((size_t)(b * S_ + sRow)) * D_ + h * 64 + sCol;
    const u16* gV = Vt + ((size_t)((b * 16 + h) * 64 + sRow)) * S_ + sCol;

    float mrow = -1e30f, lrow = 0.f;
    floatx4 o[4];                                // o[dhs][reg], O^T layout
    const floatx4 z = {0.f, 0.f, 0.f, 0.f};
#pragma unroll
    for (int i = 0; i < 4; ++i) o[i] = z;

    const float* bp = mbias + b * S_;

    for (int kt = 0; kt < S_; kt += 64) {
        __syncthreads();
        *(short8*)&Kt[sRow * 72 + sCol]     = *(const short8*)(gK);
        *(short8*)&Kt[sRow * 72 + sCol + 8] = *(const short8*)(gK + 8);
        *(short8*)&Vs[sRow * 72 + sCol]     = *(const short8*)(gV);
        *(short8*)&Vs[sRow * 72 + sCol + 8] = *(const short8*)(gV + 8);
        gK += (size_t)64 * D_; gV += 64;
        __syncthreads();

        // S^T (64 keys x 16 queries): A = K-frag, B = Q-frag
        floatx4 st[4];
#pragma unroll
        for (int ks = 0; ks < 4; ++ks) {
            floatx4 s = z;
            const short8 ak0 = *(const short8*)&Kt[(ks * 16 + lm) * 72 + quad * 8];
            const short8 ak1 = *(const short8*)&Kt[(ks * 16 + lm) * 72 + 32 + quad * 8];
            s = __builtin_amdgcn_mfma_f32_16x16x32_bf16(ak0, bq0, s, 0, 0, 0);
            s = __builtin_amdgcn_mfma_f32_16x16x32_bf16(ak1, bq1, s, 0, 0, 0);
            const float4 mb = *(const float4*)&bp[kt + ks * 16 + quad * 4];
            st[ks][0] = s[0] * 0.125f + mb.x;
            st[ks][1] = s[1] * 0.125f + mb.y;
            st[ks][2] = s[2] * 0.125f + mb.z;
            st[ks][3] = s[3] * 0.125f + mb.w;
        }
        // online softmax: 16 in-lane values + cross-quad (xor 16, 32)
        float tm = st[0][0];
#pragma unroll
        for (int ks = 0; ks < 4; ++ks)
#pragma unroll
            for (int r = 0; r < 4; ++r) tm = fmaxf(tm, st[ks][r]);
        tm = fmaxf(tm, __shfl_xor(tm, 16));
        tm = fmaxf(tm, __shfl_xor(tm, 32));
        const float mn = fmaxf(mrow, tm);
        const float alpha = __expf(mrow - mn);
        mrow = mn;
        float rs = 0.f;
#pragma unroll
        for (int ks = 0; ks < 4; ++ks)
#pragma unroll
            for (int r = 0; r < 4; ++r) {
                const float p = __expf(st[ks][r] - mn);
                st[ks][r] = p; rs += p;
            }
        rs += __shfl_xor(rs, 16);
        rs += __shfl_xor(rs, 32);
        lrow = lrow * alpha + rs;
#pragma unroll
        for (int d = 0; d < 4; ++d) o[d] *= alpha;

        // P^T B-frags for 16x16x16: k = quad*4+j (key), n = lm (query)
        short4v pb[4];
#pragma unroll
        for (int ks = 0; ks < 4; ++ks) {
            short4v t;
            t[0] = (short)f2bf(st[ks][0]);
            t[1] = (short)f2bf(st[ks][1]);
            t[2] = (short)f2bf(st[ks][2]);
            t[3] = (short)f2bf(st[ks][3]);
            pb[ks] = t;
        }
        // O^T += V^T · P^T ; V^T A-frag: m=dh (lm), k=key=quad*4+j (b64 read)
#pragma unroll
        for (int d = 0; d < 4; ++d)
#pragma unroll
            for (int ks = 0; ks < 4; ++ks) {
                const short4v av = *(const short4v*)&Vs[(d * 16 + lm) * 72 + ks * 16 + quad * 4];
                o[d] = __builtin_amdgcn_mfma_f32_16x16x16bf16_1k(av, pb[ks], o[d], 0, 0, 0);
            }
    }
    // O^T C-layout: row=dh=quad*4+reg, col=query=lm -> 4 contiguous u16/store
    const float inv = 1.f / lrow;
    u16* op = O + ((size_t)(b * S_ + q0 + w * 16 + lm)) * D_ + h * 64 + quad * 4;
#pragma unroll
    for (int d = 0; d < 4; ++d) {
        short4v pk;
        pk[0] = (short)f2bf(o[d][0] * inv);
        pk[1] = (short)f2bf(o[d][1] * inv);
        pk[2] = (short)f2bf(o[d][2] * inv);
        pk[3] = (short)f2bf(o[d][3] * inv);
        *(short4v*)(op + d * 16) = pk;
    }
}

// ---------------------------------------------------------------------------
// out = LayerNorm(mainp + resid) * gamma + beta. gamma/beta f32.
// Safe for out == mainp (rows are block-disjoint; reads precede writes).
// ---------------------------------------------------------------------------
template<bool MAIN_F32, bool RESID_F32, bool OUT_F32>
__global__ __launch_bounds__(256) void add_ln(
    const void* __restrict__ mainp, const void* __restrict__ resid,
    const float* __restrict__ gamma, const float* __restrict__ beta,
    void* __restrict__ out)
{
    const int row = blockIdx.x;
    const size_t base = (size_t)row * D_;
    const int t = threadIdx.x;
    const int w = t >> 6, lane = t & 63;
    float v[4];
#pragma unroll
    for (int i = 0; i < 4; ++i) {
        const int c = i * 256 + t;
        const float mv = MAIN_F32 ? ((const float*)mainp)[base + c]
                                  : bf2f(((const u16*)mainp)[base + c]);
        const float rv = RESID_F32 ? ((const float*)resid)[base + c]
                                   : bf2f(((const u16*)resid)[base + c]);
        v[i] = mv + rv;
    }
    float s = v[0] + v[1] + v[2] + v[3];
#pragma unroll
    for (int off = 32; off >= 1; off >>= 1) s += __shfl_xor(s, off);
    __shared__ float red[8];
    if (lane == 0) red[w] = s;
    __syncthreads();
    const float mean = (red[0] + red[1] + red[2] + red[3]) * (1.0f / D_);
    float q = 0.f;
#pragma unroll
    for (int i = 0; i < 4; ++i) { const float dd = v[i] - mean; q += dd * dd; }
#pragma unroll
    for (int off = 32; off >= 1; off >>= 1) q += __shfl_xor(q, off);
    if (lane == 0) red[4 + w] = q;
    __syncthreads();
    const float var = (red[4] + red[5] + red[6] + red[7]) * (1.0f / D_);
    const float rstd = rsqrtf(var + 1e-5f);
#pragma unroll
    for (int i = 0; i < 4; ++i) {
        const int c = i * 256 + t;
        const float o = (v[i] - mean) * rstd * gamma[c] + beta[c];
        if (OUT_F32) ((float*)out)[base + c] = o;
        else         ((u16*)out)[base + c] = f2bf(o);
    }
}

// ---------------------------------------------------------------------------
extern "C" void kernel_launch(void* const* d_in, const int* in_sizes, int n_in,
                              void* d_out, int out_size, void* d_ws, size_t ws_size,
                              hipStream_t stream)
{
    const float* x   = (const float*)d_in[0];
    const int* mask  = (const int*)d_in[1];
    const float* WQ = (const float*)d_in[2];  const float* bQ = (const float*)d_in[3];
    const float* WK = (const float*)d_in[4];  const float* bK = (const float*)d_in[5];
    const float* WV = (const float*)d_in[6];  const float* bV = (const float*)d_in[7];
    const float* WY = (const float*)d_in[8];  const float* bY = (const float*)d_in[9];
    const float* ln1w = (const float*)d_in[10]; const float* ln1b = (const float*)d_in[11];
    const float* ln2w = (const float*)d_in[12]; const float* ln2b = (const float*)d_in[13];
    const float* W1 = (const float*)d_in[14]; const float* b1 = (const float*)d_in[15];
    const float* W2 = (const float*)d_in[16]; const float* b2 = (const float*)d_in[17];

    // Workspace (peak 48 MB + 16 KB bias):
    //  xb[0,8) -> W1t -> W2t ; Wqkvt[8,14) -> WYt[8,10) -> hbf[8,16)
    //  Qb[16,24) -> Yp -> G ; Kb[24,32) -> G ; Vt[32,40) -> G ; Yat[40,48) -> G
    char* ws = (char*)d_ws;
    u16* xb    = (u16*)(ws + 0  * MB_);
    u16* Wqkvt = (u16*)(ws + 8  * MB_);        // 6 MB: [WQ^T; WK^T; WV^T]
    u16* Qb    = (u16*)(ws + 16 * MB_);
    u16* Kb    = (u16*)(ws + 24 * MB_);
    u16* Vt    = (u16*)(ws + 32 * MB_);        // [b][h][dh][s]
    u16* Yat   = (u16*)(ws + 40 * MB_);
    u16* WYt   = (u16*)(ws + 8  * MB_);        // after Wqkvt dead
    u16* Yp    = (u16*)(ws + 16 * MB_);        // after Qb dead
    u16* hbf   = (u16*)(ws + 8  * MB_);        // after WYt dead
    u16* W1t   = (u16*)(ws + 0  * MB_);        // after xb dead
    u16* G     = (u16*)(ws + 16 * MB_);        // after Yp/Kb/Vt/Yat dead
    u16* W2t   = (u16*)(ws + 0  * MB_);        // after W1t dead
    float* mb  = (float*)(ws + 48 * MB_);      // 16 KB mask bias

    const dim3 tb(32, 8);

    cvt_f32_bf16<<<(M_*D_)/1024, 256, 0, stream>>>(x, xb, M_*D_);
    mask_bias<<<(B_*S_)/256, 256, 0, stream>>>(mask, mb, B_*S_);
    transpose_cvt<<<dim3(D_/32, D_/32), tb, 0, stream>>>(WQ, Wqkvt,                 D_, D_);
    transpose_cvt<<<dim3(D_/32, D_/32), tb, 0, stream>>>(WK, Wqkvt + (size_t)D_*D_, D_, D_);
    transpose_cvt<<<dim3(D_/32, D_/32), tb, 0, stream>>>(WV, Wqkvt + (size_t)2*D_*D_, D_, D_);

    gemm_qkv<<<dim3(3*D_/128, M_/128), 256, 0, stream>>>(xb, Wqkvt, bQ, bK, bV, Qb, Kb, Vt);

    attn_kernel<<<dim3(S_/64, B_*H_), 256, 0, stream>>>(Qb, Kb, Vt, mb, Yat);

    transpose_cvt<<<dim3(D_/32, D_/32), tb, 0, stream>>>(WY, WYt, D_, D_);
    gemm_bt<false,false><<<dim3(D_/128, M_/128), 256, 0, stream>>>(Yat, WYt, bY, Yp, M_, D_, D_);

    add_ln<false,true,false><<<M_, 256, 0, stream>>>(Yp, x, ln1w, ln1b, hbf);

    transpose_cvt<<<dim3(FF_/32, D_/32), tb, 0, stream>>>(W1, W1t, D_, FF_);
    gemm_bt<true,false><<<dim3(FF_/128, M_/128), 256, 0, stream>>>(hbf, W1t, b1, G, M_, FF_, D_);

    transpose_cvt<<<dim3(D_/32, FF_/32), tb, 0, stream>>>(W2, W2t, FF_, D_);
    gemm_bt<false,true><<<dim3(D_/128, M_/128), 256, 0, stream>>>(G, W2t, b2, (float*)d_out, M_, D_, FF_);

    add_ln<true,false,true><<<M_, 256, 0, stream>>>((float*)d_out, hbf, ln2w, ln2b, d_out);
}